// Round 11
// baseline (36.161 us; speedup 1.0000x reference)
//
#include <hip/hip_runtime.h>
#include <hip/hip_fp16.h>
#include <math.h>

#define W 384
#define H 384
#define NB 32
#define NPIX (W*H)

#define BAND 16
#define NBANDS (H/BAND)            // 24
#define NBLK1 (NB*NBANDS)          // 768 blocks = 3/CU exactly
#define LSTR 416                   // 16 zero pad | 384 | 16 replicate pad

#define NBLK2 1536                 // K2: 256 thr, 4 waves; 48 blocks/img
#define CGPI 48                    // blocks per image

// ---------------------------------------------------------------------------
// K1: per 16-row band: row-prefix -> band 2D prefix S (LDS, reg-chained) ->
// V_k[y][x] = S[y][x+k] - S[y][x-k-1]  (fp16, horizontal clamps via pads)
// ---------------------------------------------------------------------------
__global__ __launch_bounds__(384) void band_v_kernel(
    const float* __restrict__ mask,
    __half* __restrict__ V3, __half* __restrict__ V15, __half* __restrict__ V31)
{
    __shared__ float lds[BAND][LSTR];     // 26,624 B

    const int tid  = threadIdx.x;
    const int wave = tid >> 6;
    const int lane = tid & 63;
    const int bid  = blockIdx.x;
    const int b    = (bid & 7) + 8 * ((bid >> 3) / NBANDS);   // img%8 == XCD
    const int band = (bid >> 3) % NBANDS;
    const int y0   = band * BAND;

    const float* mimg = mask + (size_t)b * NPIX;

    // phase 0: zero the 16-col left pads (16 rows x 16 = 256 slots)
    if (tid < 256) { lds[tid >> 4][tid & 15] = 0.0f; }

    // phase 1: row prefix of each band row into lds[r][16..399]
    {
        const int x0 = lane * 6;
        #pragma unroll
        for (int i = 0; i < 3; ++i) {
            const int r = wave + i * 6;
            if (r < BAND) {
                const float2* src = (const float2*)(mimg + (size_t)(y0 + r) * W + x0);
                const float2 q0 = src[0], q1 = src[1], q2 = src[2];
                const float s0 = q0.x;
                const float s1 = s0 + q0.y;
                const float s2 = s1 + q1.x;
                const float s3 = s2 + q1.y;
                const float s4 = s3 + q2.x;
                const float s5 = s4 + q2.y;
                float ss = s5;
                #pragma unroll
                for (int d = 1; d < 64; d <<= 1) {
                    float t = __shfl_up(ss, d);
                    if (lane >= d) ss += t;
                }
                const float base = ss - s5;
                float2* dst = (float2*)&lds[r][16 + x0];
                dst[0] = make_float2(base + s0, base + s1);
                dst[1] = make_float2(base + s2, base + s3);
                dst[2] = make_float2(base + s4, base + s5);
            }
        }
    }
    __syncthreads();

    // phase 2: column prefix via registers (independent reads, reg chain)
    {
        const int c = 16 + tid;            // tid in [0,384): every column
        float v[BAND];
        #pragma unroll
        for (int r = 0; r < BAND; ++r) v[r] = lds[r][c];
        float acc = 0.0f;
        #pragma unroll
        for (int r = 0; r < BAND; ++r) { acc += v[r]; v[r] = acc; }
        #pragma unroll
        for (int r = 0; r < BAND; ++r) lds[r][c] = v[r];
    }
    __syncthreads();

    // phase 3: right pads = S[r][383] (col 399) replicated to cols 400..415
    if (tid < 256) {
        const int r = tid >> 4, j = tid & 15;
        lds[r][400 + j] = lds[r][399];
    }
    __syncthreads();

    // phase 4: V taps + half2 store. thread -> (col pair, row half)
    {
        const int cp = tid % 192;          // col pair: cols 2cp, 2cp+1
        const int hf = tid / 192;          // rows hf*8 .. hf*8+7
        const int c0 = 16 + 2 * cp;
        const size_t obase = (size_t)b * NPIX + (size_t)y0 * W + 2 * cp;
        #pragma unroll
        for (int rr = 0; rr < 8; ++rr) {
            const int r = hf * 8 + rr;
            const float* R = lds[r];
            const __half2 h3  = __floats2half2_rn(R[c0+1]  - R[c0-2],  R[c0+2]  - R[c0-1]);
            const __half2 h15 = __floats2half2_rn(R[c0+7]  - R[c0-8],  R[c0+8]  - R[c0-7]);
            const __half2 h31 = __floats2half2_rn(R[c0+15] - R[c0-16], R[c0+16] - R[c0-15]);
            const size_t o = obase + (size_t)r * W;
            *(__half2*)(V3  + o) = h3;
            *(__half2*)(V15 + o) = h15;
            *(__half2*)(V31 + o) = h31;
        }
    }
}

// ---------------------------------------------------------------------------
// K2: fused loss. 6 cols/lane = one full row per wave; y is wave-uniform
// (forced scalar via readfirstlane) -> scalar tap branches + s+v addressing.
// ---------------------------------------------------------------------------
struct __align__(4) H6 { __half2 a, b, c; };   // 12 B tap (6 cols fp16)

__device__ inline void tap6_add(const __half* vp, int row, int xb, float o[6]) {
    const H6 h = *(const H6*)(vp + (size_t)row * W + xb);
    const float2 fa = __half22float2(h.a);
    const float2 fb = __half22float2(h.b);
    const float2 fc = __half22float2(h.c);
    o[0] += fa.x; o[1] += fa.y; o[2] += fb.x; o[3] += fb.y; o[4] += fc.x; o[5] += fc.y;
}
__device__ inline void tap6_sub(const __half* vp, int row, int xb, float o[6]) {
    const H6 h = *(const H6*)(vp + (size_t)row * W + xb);
    const float2 fa = __half22float2(h.a);
    const float2 fb = __half22float2(h.b);
    const float2 fc = __half22float2(h.c);
    o[0] -= fa.x; o[1] -= fa.y; o[2] -= fb.x; o[3] -= fb.y; o[4] -= fc.x; o[5] -= fc.y;
}

// box over rows [y-r, y+r] (zero-padded) from band-local column prefix V
__device__ inline void boxrow(const __half* vp, int y, int r, int xb, float o[6]) {
    #pragma unroll
    for (int c = 0; c < 6; ++c) o[c] = 0.0f;
    const int y1 = min(y + r, H - 1);
    tap6_add(vp, y1, xb, o);
    const int ylo = y - r - 1;
    int s = 0;
    if (ylo >= 0) { tap6_sub(vp, ylo, xb, o); s = ylo >> 4; }   // uniform branch
    const int n = (y1 >> 4) - s;
    if (n >= 1) tap6_add(vp, s * 16 + 15, xb, o);               // band total(s)
    if (n >= 2) tap6_add(vp, s * 16 + 31, xb, o);
}

__global__ __launch_bounds__(256) void loss_kernel(
    const float* __restrict__ pred, const float* __restrict__ mask,
    const __half* __restrict__ V3, const __half* __restrict__ V15,
    const __half* __restrict__ V31, float* __restrict__ partials)
{
    const int tid  = threadIdx.x;
    const int wave = tid >> 6;
    const int lane = tid & 63;
    const int bid  = blockIdx.x;
    const int j    = bid >> 3;                    // 0..191
    const int b    = (bid & 7) + 8 * (j / CGPI);  // img%8 == XCD
    const int cg   = j % CGPI;                    // 0..47
    // force wave-uniform chunk into an SGPR: rows 2*chunk, 2*chunk+1
    const int chunkU = __builtin_amdgcn_readfirstlane(cg * 4 + wave);
    const int xb   = lane * 6;                    // col base (6 cols/lane)

    const size_t ibase = (size_t)b * NPIX;
    const float* mimg = mask + ibase;
    const float* pimg = pred + ibase;
    const __half* V3i  = V3  + ibase;
    const __half* V15i = V15 + ibase;
    const __half* V31i = V31 + ibase;

    float pw = 0.f, pin = 0.f, pun = 0.f, pb = 0.f, pm = 0.f;
    const float i9 = 1.0f/9.0f, i225 = 1.0f/225.0f, i961 = 1.0f/961.0f;

    #pragma unroll
    for (int hh = 0; hh < 2; ++hh) {
        const int y = 2 * chunkU + hh;            // scalar

        float b3[6], b15[6], b31[6];
        boxrow(V3i,  y, 1,  xb, b3);
        boxrow(V15i, y, 7,  xb, b15);
        boxrow(V31i, y, 15, xb, b31);

        const float2* m2 = (const float2*)(mimg + (size_t)y * W + xb);
        const float2* p2 = (const float2*)(pimg + (size_t)y * W + xb);
        const float2 m01 = m2[0], m23 = m2[1], m45 = m2[2];
        const float2 p01 = p2[0], p23 = p2[1], p45 = p2[2];
        const float mm[6] = { m01.x, m01.y, m23.x, m23.y, m45.x, m45.y };
        const float pp[6] = { p01.x, p01.y, p23.x, p23.y, p45.x, p45.y };

        #pragma unroll
        for (int c = 0; c < 6; ++c) {
            const float m = mm[c], p = pp[c];
            const float w = fabsf(b3[c]*i9 - m) + fabsf(b15[c]*i225 - m) + fabsf(b31[c]*i961 - m);
            const float weit = 1.0f + 0.5f * w * m;
            pw  += weit;
            pin += p * m * weit;
            pun += (p + m) * weit;
            pb  -= m * __logf(p) + (1.0f - m) * __logf(1.0f - p);
            pm  += fabsf(p - m);
        }
    }

    // deterministic wave butterfly
    #pragma unroll
    for (int off = 32; off >= 1; off >>= 1) {
        pw  += __shfl_xor(pw,  off);
        pin += __shfl_xor(pin, off);
        pun += __shfl_xor(pun, off);
        pb  += __shfl_xor(pb,  off);
        pm  += __shfl_xor(pm,  off);
    }
    __shared__ float red[4][5];
    if (lane == 0) {
        red[wave][0]=pw; red[wave][1]=pin; red[wave][2]=pun; red[wave][3]=pb; red[wave][4]=pm;
    }
    __syncthreads();
    if (tid == 0) {
        float* o = partials + (size_t)(b * CGPI + cg) * 8;
        o[0]=red[0][0]+red[1][0]+red[2][0]+red[3][0];
        o[1]=red[0][1]+red[1][1]+red[2][1]+red[3][1];
        o[2]=red[0][2]+red[1][2]+red[2][2]+red[3][2];
        o[3]=red[0][3]+red[1][3]+red[2][3]+red[3][3];
        o[4]=red[0][4]+red[1][4]+red[2][4]+red[3][4];
    }
}

// ---------------------------------------------------------------------------
// K3: finalize. 256 threads, fp64, fixed order -> deterministic scalar.
// ---------------------------------------------------------------------------
__global__ __launch_bounds__(256) void finalize_kernel(
    const float* __restrict__ partials, float* __restrict__ out)
{
    __shared__ double sB[4], sM[4];
    __shared__ double sw_[NB], si_[NB], su_[NB];

    const int tid = threadIdx.x;
    const int i   = tid >> 3;                 // image 0..31
    const int s   = tid & 7;

    double Sw = 0, Si = 0, Su = 0, Bc = 0, Ma = 0;
    for (int k = s; k < CGPI; k += 8) {
        const float* q = partials + (size_t)(i * CGPI + k) * 8;
        Sw += (double)q[0]; Si += (double)q[1]; Su += (double)q[2];
    }
    for (int k = tid; k < NBLK2; k += 256) {
        const float* q = partials + (size_t)k * 8;
        Bc += (double)q[3]; Ma += (double)q[4];
    }
    #pragma unroll
    for (int d = 4; d >= 1; d >>= 1) {
        Sw += __shfl_down(Sw, d);
        Si += __shfl_down(Si, d);
        Su += __shfl_down(Su, d);
    }
    if (s == 0) { sw_[i] = Sw; si_[i] = Si; su_[i] = Su; }
    #pragma unroll
    for (int d = 32; d >= 1; d >>= 1) {
        Bc += __shfl_down(Bc, d);
        Ma += __shfl_down(Ma, d);
    }
    if ((tid & 63) == 0) { sB[tid >> 6] = Bc; sM[tid >> 6] = Ma; }
    __syncthreads();

    if (tid < 64) {
        double wiou = 0.0, ratio = 0.0;
        if (tid < NB) {
            const double w = sw_[tid], ii = si_[tid], u = su_[tid];
            wiou  = 1.0 - ii / (u - ii);
            ratio = w / (w - (double)NPIX);
        }
        #pragma unroll
        for (int d = 32; d >= 1; d >>= 1) {
            wiou  += __shfl_down(wiou,  d);
            ratio += __shfl_down(ratio, d);
        }
        if (tid == 0) {
            const double bt  = sB[0] + sB[1] + sB[2] + sB[3];
            const double mt  = sM[0] + sM[1] + sM[2] + sM[3];
            const double tot = (double)NB * (double)NPIX;
            const double bce = bt / tot;
            const double mae = mt / tot;
            out[0] = (float)(0.7 * (bce + wiou / (double)NB + mae * ratio / (double)NB));
        }
    }
}

extern "C" void kernel_launch(void* const* d_in, const int* in_sizes, int n_in,
                              void* d_out, int out_size, void* d_ws, size_t ws_size,
                              hipStream_t stream) {
    const float* pred = (const float*)d_in[0];
    const float* mask = (const float*)d_in[1];
    float* out        = (float*)d_out;

    // ws layout: V3 | V15 | V31 (each 32*384*384 fp16 = 4.72 MB) | partials
    const size_t vplane = (size_t)NB * NPIX;           // elements
    __half* V3  = (__half*)d_ws;
    __half* V15 = V3  + vplane;
    __half* V31 = V15 + vplane;
    float* partials = (float*)(V31 + vplane);          // 1536*8*4 = 48 KB

    band_v_kernel<<<dim3(NBLK1), dim3(384), 0, stream>>>(mask, V3, V15, V31);
    loss_kernel<<<dim3(NBLK2), dim3(256), 0, stream>>>(pred, mask, V3, V15, V31, partials);
    finalize_kernel<<<dim3(1), dim3(256), 0, stream>>>(partials, out);
}

// Round 12
// 30.990 us; speedup vs baseline: 1.1669x; 1.1669x over previous
//
#include <hip/hip_runtime.h>
#include <hip/hip_fp16.h>
#include <math.h>

#define W 384
#define H 384
#define NB 32
#define NPIX (W*H)

#define BAND 16
#define NBANDS (H/BAND)            // 24
#define NBLK1 (NB*NBANDS)          // 768 blocks = 3/CU exactly
#define LSTR 416                   // 16 zero pad | 384 | 16 replicate pad

#define NBLK2 1536                 // K2: 256 thr, 4 waves; 48 blocks/img; 24 waves/CU
#define CGPI 48                    // chunk-groups (blocks) per image
#define ITERS 3                    // 3 x 256 px per wave = 768 px (2 rows) per wave

// ---------------------------------------------------------------------------
// K1: per 16-row band: row-prefix -> band 2D prefix S (LDS, reg-chained) ->
// V_k[y][x] = S[y][x+k] - S[y][x-k-1]  (fp16, horizontal clamps via pads)
// ---------------------------------------------------------------------------
__global__ __launch_bounds__(384) void band_v_kernel(
    const float* __restrict__ mask,
    __half* __restrict__ V3, __half* __restrict__ V15, __half* __restrict__ V31)
{
    __shared__ float lds[BAND][LSTR];     // 26,624 B

    const int tid  = threadIdx.x;
    const int wave = tid >> 6;
    const int lane = tid & 63;
    const int bid  = blockIdx.x;
    const int b    = (bid & 7) + 8 * ((bid >> 3) / NBANDS);   // img%8 == XCD
    const int band = (bid >> 3) % NBANDS;
    const int y0   = band * BAND;

    const float* mimg = mask + (size_t)b * NPIX;

    // phase 0: zero the 16-col left pads (16 rows x 16 = 256 slots)
    if (tid < 256) { lds[tid >> 4][tid & 15] = 0.0f; }

    // phase 1: row prefix of each band row into lds[r][16..399]
    {
        const int x0 = lane * 6;
        #pragma unroll
        for (int i = 0; i < 3; ++i) {
            const int r = wave + i * 6;
            if (r < BAND) {
                const float2* src = (const float2*)(mimg + (size_t)(y0 + r) * W + x0);
                const float2 q0 = src[0], q1 = src[1], q2 = src[2];
                const float s0 = q0.x;
                const float s1 = s0 + q0.y;
                const float s2 = s1 + q1.x;
                const float s3 = s2 + q1.y;
                const float s4 = s3 + q2.x;
                const float s5 = s4 + q2.y;
                float ss = s5;
                #pragma unroll
                for (int d = 1; d < 64; d <<= 1) {
                    float t = __shfl_up(ss, d);
                    if (lane >= d) ss += t;
                }
                const float base = ss - s5;
                float2* dst = (float2*)&lds[r][16 + x0];
                dst[0] = make_float2(base + s0, base + s1);
                dst[1] = make_float2(base + s2, base + s3);
                dst[2] = make_float2(base + s4, base + s5);
            }
        }
    }
    __syncthreads();

    // phase 2: column prefix via registers (independent reads, reg chain)
    {
        const int c = 16 + tid;            // tid in [0,384): every column
        float v[BAND];
        #pragma unroll
        for (int r = 0; r < BAND; ++r) v[r] = lds[r][c];
        float acc = 0.0f;
        #pragma unroll
        for (int r = 0; r < BAND; ++r) { acc += v[r]; v[r] = acc; }
        #pragma unroll
        for (int r = 0; r < BAND; ++r) lds[r][c] = v[r];
    }
    __syncthreads();

    // phase 3: right pads = S[r][383] (col 399) replicated to cols 400..415
    if (tid < 256) {
        const int r = tid >> 4, j = tid & 15;
        lds[r][400 + j] = lds[r][399];
    }
    __syncthreads();

    // phase 4: V taps + half2 store. thread -> (col pair, row half)
    {
        const int cp = tid % 192;          // col pair: cols 2cp, 2cp+1
        const int hf = tid / 192;          // rows hf*8 .. hf*8+7
        const int c0 = 16 + 2 * cp;
        const size_t obase = (size_t)b * NPIX + (size_t)y0 * W + 2 * cp;
        #pragma unroll
        for (int rr = 0; rr < 8; ++rr) {
            const int r = hf * 8 + rr;
            const float* R = lds[r];
            const __half2 h3  = __floats2half2_rn(R[c0+1]  - R[c0-2],  R[c0+2]  - R[c0-1]);
            const __half2 h15 = __floats2half2_rn(R[c0+7]  - R[c0-8],  R[c0+8]  - R[c0-7]);
            const __half2 h31 = __floats2half2_rn(R[c0+15] - R[c0-16], R[c0+16] - R[c0-15]);
            const size_t o = obase + (size_t)r * W;
            *(__half2*)(V3  + o) = h3;
            *(__half2*)(V15 + o) = h15;
            *(__half2*)(V31 + o) = h31;
        }
    }
}

// ---------------------------------------------------------------------------
// K2: fused loss (R10 structure). 4 cols/lane; per 256-px wave-iter:
// 10 dwordx2 V taps + 2 float4 (m,p). Slimmed math: log2-domain BCE
// (ln2 deferred to finalize), fma/abs-mod weit path.
// ---------------------------------------------------------------------------
struct __align__(8) H4 { __half2 a, b; };

__device__ inline void vtap(const __half* vp, int row, float o[4]) {
    const H4 h = *(const H4*)(vp + (size_t)row * W);
    const float2 fa = __half22float2(h.a);
    const float2 fb = __half22float2(h.b);
    o[0] = fa.x; o[1] = fa.y; o[2] = fb.x; o[3] = fb.y;
}

__global__ __launch_bounds__(256) void loss_kernel(
    const float* __restrict__ pred, const float* __restrict__ mask,
    const __half* __restrict__ V3, const __half* __restrict__ V15,
    const __half* __restrict__ V31, float* __restrict__ partials)
{
    const int tid  = threadIdx.x;
    const int wave = tid >> 6;
    const int lane = tid & 63;
    const int bid  = blockIdx.x;
    const int j    = bid >> 3;                    // 0..191
    const int b    = (bid & 7) + 8 * (j / CGPI);  // img%8 == XCD
    const int cg   = j % CGPI;                    // 0..47
    const int chunk = cg * 4 + wave;              // rows [2*chunk, 2*chunk+2)

    const size_t ibase = (size_t)b * NPIX;
    const float* mimg = mask + ibase;
    const float* pimg = pred + ibase;

    float pw = 0.f, pin = 0.f, pun = 0.f, pb = 0.f, pm = 0.f;
    // 0.5 folded into the box reciprocals (|b*k - m|*0.5 == |b*(k/2) - m/2|)
    const float i9h = 0.5f/9.0f, i225h = 0.5f/225.0f, i961h = 0.5f/961.0f;

    #pragma unroll
    for (int it = 0; it < ITERS; ++it) {
        const int q  = it * 256 + (lane << 2);    // 0..764
        const int yo = (q >= 384) ? 1 : 0;
        const int y  = (chunk << 1) + yo;
        const int x  = q - (yo ? 384 : 0);        // multiple of 4
        const size_t po = (size_t)chunk * 768 + q;

        const __half* v3x  = V3  + ibase + x;
        const __half* v15x = V15 + ibase + x;
        const __half* v31x = V31 + ibase + x;

        float b3v[4], b15v[4], b31v[4];
        // radius 1 and 7: 3-tap (span <= 15 rows -> at most one band crossing)
        {
            float t1[4], t0[4], tt[4];
            const int y1  = min(y + 1, H - 1);
            const int ylo = y - 2;
            const int y0c = ylo < 0 ? 0 : ylo;
            const int ytp = y0c | (BAND - 1);
            const float fLo = ylo >= 0 ? 1.0f : 0.0f;
            const float fC  = (ylo >= 0 && (y0c >> 4) != (y1 >> 4)) ? 1.0f : 0.0f;
            vtap(v3x, y1, t1); vtap(v3x, y0c, t0); vtap(v3x, ytp, tt);
            #pragma unroll
            for (int c = 0; c < 4; ++c) b3v[c] = t1[c] - fLo * t0[c] + fC * tt[c];
        }
        {
            float t1[4], t0[4], tt[4];
            const int y1  = min(y + 7, H - 1);
            const int ylo = y - 8;
            const int y0c = ylo < 0 ? 0 : ylo;
            const int ytp = y0c | (BAND - 1);
            const float fLo = ylo >= 0 ? 1.0f : 0.0f;
            const float fC  = (ylo >= 0 && (y0c >> 4) != (y1 >> 4)) ? 1.0f : 0.0f;
            vtap(v15x, y1, t1); vtap(v15x, y0c, t0); vtap(v15x, ytp, tt);
            #pragma unroll
            for (int c = 0; c < 4; ++c) b15v[c] = t1[c] - fLo * t0[c] + fC * tt[c];
        }
        // radius 15: 4-tap (span 31 rows -> up to two band crossings)
        {
            float t1[4], t0[4], ta[4], tb[4];
            const int y1  = min(y + 15, H - 1);
            const int ylo = y - 16;
            const int y0c = ylo < 0 ? 0 : ylo;
            const int s   = ylo >= 0 ? (y0c >> 4) : 0;
            const int n   = (y1 >> 4) - s;
            const int rt1 = s * BAND + (BAND - 1);
            const int rt2 = min(rt1 + BAND, H - 1);
            const float fLo = ylo >= 0 ? 1.0f : 0.0f;
            const float g1  = n >= 1 ? 1.0f : 0.0f;
            const float g2  = n >= 2 ? 1.0f : 0.0f;
            vtap(v31x, y1, t1); vtap(v31x, y0c, t0); vtap(v31x, rt1, ta); vtap(v31x, rt2, tb);
            #pragma unroll
            for (int c = 0; c < 4; ++c)
                b31v[c] = t1[c] - fLo * t0[c] + g1 * ta[c] + g2 * tb[c];
        }

        const float4 mv = *(const float4*)(mimg + po);
        const float4 pv = *(const float4*)(pimg + po);
        const float mm[4] = { mv.x, mv.y, mv.z, mv.w };
        const float pp[4] = { pv.x, pv.y, pv.z, pv.w };

        #pragma unroll
        for (int c = 0; c < 4; ++c) {
            const float m = mm[c], p = pp[c];
            const float hm = 0.5f * m;
            const float t3  = fmaf(b3v[c],  i9h,   -hm);
            const float t15 = fmaf(b15v[c], i225h, -hm);
            const float t31 = fmaf(b31v[c], i961h, -hm);
            const float wh  = fabsf(t3) + fabsf(t15) + fabsf(t31);  // 0.5*w
            const float weit = fmaf(wh, m, 1.0f);                   // 1 + 0.5*w*m
            pw  += weit;
            pin  = fmaf(p * m, weit, pin);
            pun  = fmaf(p + m, weit, pun);
            const float lp = __log2f(p);
            const float lq = __log2f(1.0f - p);
            pb  -= fmaf(m, lp - lq, lq);     // = m*log2(p) + (1-m)*log2(1-p)
            pm  += fabsf(p - m);
        }
    }

    // deterministic wave butterfly
    #pragma unroll
    for (int off = 32; off >= 1; off >>= 1) {
        pw  += __shfl_xor(pw,  off);
        pin += __shfl_xor(pin, off);
        pun += __shfl_xor(pun, off);
        pb  += __shfl_xor(pb,  off);
        pm  += __shfl_xor(pm,  off);
    }
    __shared__ float red[4][5];
    if (lane == 0) {
        red[wave][0]=pw; red[wave][1]=pin; red[wave][2]=pun; red[wave][3]=pb; red[wave][4]=pm;
    }
    __syncthreads();
    if (tid == 0) {
        float* o = partials + (size_t)(b * CGPI + cg) * 8;
        o[0]=red[0][0]+red[1][0]+red[2][0]+red[3][0];
        o[1]=red[0][1]+red[1][1]+red[2][1]+red[3][1];
        o[2]=red[0][2]+red[1][2]+red[2][2]+red[3][2];
        o[3]=red[0][3]+red[1][3]+red[2][3]+red[3][3];
        o[4]=red[0][4]+red[1][4]+red[2][4]+red[3][4];
    }
}

// ---------------------------------------------------------------------------
// K3: finalize. 256 threads, fp64, fixed order -> deterministic scalar.
// pb partials are in log2 domain -> multiply by ln2 here (once).
// ---------------------------------------------------------------------------
__global__ __launch_bounds__(256) void finalize_kernel(
    const float* __restrict__ partials, float* __restrict__ out)
{
    __shared__ double sB[4], sM[4];
    __shared__ double sw_[NB], si_[NB], su_[NB];

    const int tid = threadIdx.x;
    const int i   = tid >> 3;                 // image 0..31
    const int s   = tid & 7;

    double Sw = 0, Si = 0, Su = 0, Bc = 0, Ma = 0;
    for (int k = s; k < CGPI; k += 8) {
        const float* q = partials + (size_t)(i * CGPI + k) * 8;
        Sw += (double)q[0]; Si += (double)q[1]; Su += (double)q[2];
    }
    for (int k = tid; k < NBLK2; k += 256) {
        const float* q = partials + (size_t)k * 8;
        Bc += (double)q[3]; Ma += (double)q[4];
    }
    #pragma unroll
    for (int d = 4; d >= 1; d >>= 1) {
        Sw += __shfl_down(Sw, d);
        Si += __shfl_down(Si, d);
        Su += __shfl_down(Su, d);
    }
    if (s == 0) { sw_[i] = Sw; si_[i] = Si; su_[i] = Su; }
    #pragma unroll
    for (int d = 32; d >= 1; d >>= 1) {
        Bc += __shfl_down(Bc, d);
        Ma += __shfl_down(Ma, d);
    }
    if ((tid & 63) == 0) { sB[tid >> 6] = Bc; sM[tid >> 6] = Ma; }
    __syncthreads();

    if (tid < 64) {
        double wiou = 0.0, ratio = 0.0;
        if (tid < NB) {
            const double w = sw_[tid], ii = si_[tid], u = su_[tid];
            wiou  = 1.0 - ii / (u - ii);
            ratio = w / (w - (double)NPIX);
        }
        #pragma unroll
        for (int d = 32; d >= 1; d >>= 1) {
            wiou  += __shfl_down(wiou,  d);
            ratio += __shfl_down(ratio, d);
        }
        if (tid == 0) {
            const double bt  = (sB[0] + sB[1] + sB[2] + sB[3]) * 0.6931471805599453; // ln2
            const double mt  = sM[0] + sM[1] + sM[2] + sM[3];
            const double tot = (double)NB * (double)NPIX;
            const double bce = bt / tot;
            const double mae = mt / tot;
            out[0] = (float)(0.7 * (bce + wiou / (double)NB + mae * ratio / (double)NB));
        }
    }
}

extern "C" void kernel_launch(void* const* d_in, const int* in_sizes, int n_in,
                              void* d_out, int out_size, void* d_ws, size_t ws_size,
                              hipStream_t stream) {
    const float* pred = (const float*)d_in[0];
    const float* mask = (const float*)d_in[1];
    float* out        = (float*)d_out;

    // ws layout: V3 | V15 | V31 (each 32*384*384 fp16 = 4.72 MB) | partials
    const size_t vplane = (size_t)NB * NPIX;           // elements
    __half* V3  = (__half*)d_ws;
    __half* V15 = V3  + vplane;
    __half* V31 = V15 + vplane;
    float* partials = (float*)(V31 + vplane);          // 1536*8*4 = 48 KB

    band_v_kernel<<<dim3(NBLK1), dim3(384), 0, stream>>>(mask, V3, V15, V31);
    loss_kernel<<<dim3(NBLK2), dim3(256), 0, stream>>>(pred, mask, V3, V15, V31, partials);
    finalize_kernel<<<dim3(1), dim3(256), 0, stream>>>(partials, out);
}